// Round 5
// baseline (232.498 us; speedup 1.0000x reference)
//
#include <hip/hip_runtime.h>
#include <hip/hip_bf16.h>
#include <stdint.h>

typedef unsigned short u16;
typedef short short8 __attribute__((ext_vector_type(8)));
typedef short short4v __attribute__((ext_vector_type(4)));
typedef float floatx4 __attribute__((ext_vector_type(4)));

__device__ __forceinline__ float b2f(u16 v) {
  union { unsigned int u; float f; } c; c.u = ((unsigned int)v) << 16; return c.f;
}
__device__ __forceinline__ u16 f2b(float f) {
  union { float f; unsigned int u; } c; c.f = f;
  unsigned int u = c.u;
  return (u16)((u + 0x7fffu + ((u >> 16) & 1u)) >> 16);  // RNE
}

// async global->LDS, 16B per lane. LDS dest must be wave-uniform base + lane*16.
__device__ __forceinline__ void gld_lds16(const u16* g, u16* l) {
  __builtin_amdgcn_global_load_lds(
      (const __attribute__((address_space(1))) unsigned int*)g,
      (__attribute__((address_space(3))) unsigned int*)l,
      16, 0, 0);
}

// ---------------------------------------------------------------------------
// Fused prep: x fp32->bf16 (blocks 0..6143), w_attn T (6144..6575),
// w_proj T (6576..6719). Transposes also convert fp32->bf16.
// ---------------------------------------------------------------------------
__device__ __forceinline__ void tile_transpose_f2b(
    const float* __restrict__ in, u16* __restrict__ out,
    int inRS, int outRS, int rb, int cb, int tid)
{
  __shared__ __align__(16) u16 t[64][72];
  const int r = tid >> 2, sg = tid & 3;
  const float* ip = in + (long)(rb + r) * inRS + cb + sg * 16;
#pragma unroll
  for (int i = 0; i < 16; i += 4) {
    float4 f = *(const float4*)(ip + i);
    t[r][sg * 16 + i]     = f2b(f.x);
    t[r][sg * 16 + i + 1] = f2b(f.y);
    t[r][sg * 16 + i + 2] = f2b(f.z);
    t[r][sg * 16 + i + 3] = f2b(f.w);
  }
  __syncthreads();
  short8 v0, v1;
#pragma unroll
  for (int i = 0; i < 8; i++) v0[i] = (short)t[sg * 16 + i][r];
#pragma unroll
  for (int i = 0; i < 8; i++) v1[i] = (short)t[sg * 16 + 8 + i][r];
  *(short8*)(out + (long)(cb + r) * outRS + rb + sg * 16)     = v0;
  *(short8*)(out + (long)(cb + r) * outRS + rb + sg * 16 + 8) = v1;
}

__global__ __launch_bounds__(256) void prep(
    const float* __restrict__ x, u16* __restrict__ xb,
    const float* __restrict__ w_attn, u16* __restrict__ wTa,
    const float* __restrict__ w_proj, u16* __restrict__ wTp)
{
  const int bid = blockIdx.x, tid = threadIdx.x;
  if (bid < 6144) {
    int i = (bid * 256 + tid) * 4;
    float4 f = *(const float4*)(x + i);
    short4v v;
    v[0] = (short)f2b(f.x); v[1] = (short)f2b(f.y);
    v[2] = (short)f2b(f.z); v[3] = (short)f2b(f.w);
    *(short4v*)(xb + i) = v;
  } else if (bid < 6576) {
    int t = bid - 6144;                 // 36 x 12 tiles of w_attn [768][2304]
    tile_transpose_f2b(w_attn, wTa, 2304, 768, (t / 36) * 64, (t % 36) * 64, tid);
  } else {
    int t = bid - 6576;                 // 12 x 12 tiles of w_proj [768][768]
    tile_transpose_f2b(w_proj, wTp, 768, 768, (t / 12) * 64, (t % 12) * 64, tid);
  }
}

// ---------------------------------------------------------------------------
// R12 pipelined GEMM template: C[8192][*] = A[8192][768] * Bt[*][768]^T + bias.
// Tile 128 x BN, BK=32, 3 LDS slots, 384 thr = 6 waves (2M x 3N).
// Grid 512 = (8192/128) x (2304/BN or 768/BN = 8) = EXACTLY 2 blocks/CU
// co-resident (LDS 78 KiB at BN=288 -> 2 fit). Rationale: every 1-block/CU
// variant (R8-R11) capped at MfmaUtil <=24% -- intra-block stalls had nothing
// to overlap with (m114 mechanism). 2 blocks/CU restores cross-block overlap.
//
// Pipeline: distance-2 prefetch into slot (j+2)%3 (slot last read in tile
// j-1, whose reads completed before the barrier ending j-1). Boundary =
// counted vmcnt(L) (L = own per-tile loads; wave-uniform), never 0 until the
// 2-tile tail; ONE barrier per K-tile. setprio(1) around MFMA clusters.
//
// LDS swizzle (verified 0 conflicts R8-R11): elem (row, octet o) at
// row*32 + ((o ^ ((row>>1)&3))<<3); inverse permutation pre-applied to the
// GLOBAL source column; LDS dest stays linear for global_load_lds.
// XCD swizzle: 512 = 8 XCDs x 64: each XCD gets 8 row-panels x 8 col-tiles.
// ---------------------------------------------------------------------------
__device__ __forceinline__ void store_out(u16* p, float v)  { *p = f2b(v); }
__device__ __forceinline__ void store_out(float* p, float v) { *p = v; }

#define QKV_K 768
#define QKV_NT 24   // 768/32
#define VMW(n) asm volatile("s_waitcnt vmcnt(" #n ")" ::: "memory")

template <typename OT, int BN, bool SPLIT>
__global__ __launch_bounds__(384, 3) void gemm_pipe(
    const u16* __restrict__ A, const u16* __restrict__ Bt,
    const float* __restrict__ bias, OT* __restrict__ C, u16* __restrict__ vT,
    int ldc)
{
  constexpr int NF = BN / 48;              // frags per wave: 288->6, 96->2
  constexpr int NF1 = (NF < 3) ? NF : 3;   // phase-A frags
  __shared__ __align__(16) u16 sA[3][128 * 32];
  __shared__ __align__(16) u16 sB[3][BN * 32];

  const int bid = blockIdx.x;
  const int wg = (bid & 7) * 64 + (bid >> 3);   // XCD-contiguous
  const int bx = wg & 7;        // col tile 0..7
  const int by = wg >> 3;       // row tile 0..63

  const int tid = threadIdx.x;
  const int lane = tid & 63;
  const int l15 = lane & 15, q = lane >> 4;
  const int wave = tid >> 6;          // 0..5
  const int wm = (wave / 3) * 64;     // 2 M-groups
  const int wn = (wave % 3) * (BN / 3);
  const long rowbase = (long)by * 128;
  const long colbase = (long)bx * BN;
  const int xq = ((q ^ ((l15 >> 1) & 3)) << 3);   // swizzled k-octet (u16)

  // staging chunks (16B each): row = c>>2, octet = c&3,
  // pre-swizzled global octet = (c&3)^((c>>3)&3)
  const int cA0 = tid, cA1 = 384 + tid;            // A: 512 chunks
  const int cB0 = tid, cB1 = 384 + tid, cB2 = 768 + tid;  // B: BN*4 chunks
  const bool hasA1 = (tid < 128);   // wave-uniform (waves 0-1)
  const u16* pa0 = A + (rowbase + (cA0 >> 2)) * QKV_K + ((((cA0 & 3) ^ ((cA0 >> 3) & 3))) << 3);
  const u16* pa1 = A + (rowbase + (cA1 >> 2)) * QKV_K + ((((cA1 & 3) ^ ((cA1 >> 3) & 3))) << 3);
  const u16* pb0 = Bt + (colbase + (cB0 >> 2)) * QKV_K + ((((cB0 & 3) ^ ((cB0 >> 3) & 3))) << 3);
  const u16* pb1 = Bt + (colbase + (cB1 >> 2)) * QKV_K + ((((cB1 & 3) ^ ((cB1 >> 3) & 3))) << 3);
  const u16* pb2 = Bt + (colbase + (cB2 >> 2)) * QKV_K + ((((cB2 & 3) ^ ((cB2 >> 3) & 3))) << 3);

  auto STAGE = [&](int t, int s) {
    const long k0 = (long)t * 32;
    gld_lds16(pa0 + k0, &sA[s][cA0 * 8]);
    if (hasA1) gld_lds16(pa1 + k0, &sA[s][cA1 * 8]);
    gld_lds16(pb0 + k0, &sB[s][cB0 * 8]);
    if constexpr (BN == 288) {
      gld_lds16(pb1 + k0, &sB[s][cB1 * 8]);
      gld_lds16(pb2 + k0, &sB[s][cB2 * 8]);
    }
  };
  // counted wait: leave own newest-tile loads outstanding (L per tile)
  auto WAIT_STEADY = [&]() {
    if constexpr (BN == 288) { if (hasA1) { VMW(5); } else { VMW(4); } }
    else                     { if (hasA1) { VMW(3); } else { VMW(2); } }
  };

  floatx4 acc[4][NF];
#pragma unroll
  for (int i = 0; i < 4; i++)
#pragma unroll
    for (int n = 0; n < NF; n++) acc[i][n] = (floatx4){0.f, 0.f, 0.f, 0.f};

  // prologue: tiles 0,1 -> slots 0,1; wait own tile-0 loads (tile 1 in flight)
  STAGE(0, 0); STAGE(1, 1);
  WAIT_STEADY();
  __builtin_amdgcn_s_barrier();

#pragma unroll 3
  for (int j = 0; j < QKV_NT; ++j) {
    const int slot = j % 3;
    const u16* ap = sA[slot];
    const u16* bp = sB[slot];

    // phase A: NF1 B-frags + 4 A-frags, stage tile j+2, 4*NF1 MFMA
    short8 bf[NF1], af[4];
#pragma unroll
    for (int nt = 0; nt < NF1; nt++)
      bf[nt] = *(const short8*)(bp + (wn + nt * 16 + l15) * 32 + xq);
#pragma unroll
    for (int mt = 0; mt < 4; mt++)
      af[mt] = *(const short8*)(ap + (wm + mt * 16 + l15) * 32 + xq);
    if (j + 2 < QKV_NT) STAGE(j + 2, (j + 2) % 3);
    __builtin_amdgcn_s_setprio(1);
#pragma unroll
    for (int mt = 0; mt < 4; mt++)
#pragma unroll
      for (int nt = 0; nt < NF1; nt++)
        acc[mt][nt] = __builtin_amdgcn_mfma_f32_16x16x32_bf16(af[mt], bf[nt], acc[mt][nt], 0, 0, 0);
    __builtin_amdgcn_s_setprio(0);

    if constexpr (NF == 6) {
      // phase B: 3 more B-frags (cols wn+48..wn+95), 12 MFMA
#pragma unroll
      for (int nt = 0; nt < 3; nt++)
        bf[nt] = *(const short8*)(bp + (wn + 48 + nt * 16 + l15) * 32 + xq);
      __builtin_amdgcn_s_setprio(1);
#pragma unroll
      for (int mt = 0; mt < 4; mt++)
#pragma unroll
        for (int nt = 0; nt < 3; nt++)
          acc[mt][3 + nt] = __builtin_amdgcn_mfma_f32_16x16x32_bf16(af[mt], bf[nt], acc[mt][3 + nt], 0, 0, 0);
      __builtin_amdgcn_s_setprio(0);
    }

    // boundary: tile j+1 must be resident; counted wait, never 0 mid-loop
    if (j < QKV_NT - 1) {
      if (j + 2 < QKV_NT) WAIT_STEADY();
      else                VMW(0);        // tail: only tile j+1 outstanding
      __builtin_amdgcn_s_barrier();
    }
  }

  // epilogue
#pragma unroll
  for (int nt = 0; nt < NF; nt++) {
    const int fragc = (int)colbase + wn + nt * 16;   // lane-invariant, 16-aligned
    const int col = fragc + l15;
    const float bv = bias[col];
    if (SPLIT && fragc >= 1536) {
      // V region -> vT[b*12+h][d][t] (packed 4-t stores)
      const long bb = rowbase >> 10;
      const int dloc = col - 1536;
      u16* op = vT + (bb * 12 + (dloc >> 6)) * 65536L + (long)(dloc & 63) * 1024;
      const int t0 = (int)(rowbase & 1023) + wm;
#pragma unroll
      for (int mt = 0; mt < 4; mt++) {
        short4v pv;
#pragma unroll
        for (int r = 0; r < 4; r++) pv[r] = (short)f2b(acc[mt][nt][r] + bv);
        *(short4v*)(op + t0 + mt * 16 + q * 4) = pv;
      }
    } else {
#pragma unroll
      for (int mt = 0; mt < 4; mt++)
#pragma unroll
        for (int r = 0; r < 4; r++) {
          const long row = rowbase + wm + mt * 16 + q * 4 + r;
          store_out(C + row * (long)ldc + col, acc[mt][nt][r] + bv);
        }
    }
  }
}
#undef VMW

// ---------------------------------------------------------------------------
// R11 flash attention, causal (unchanged). One block = (b*12+h, 128 q-rows),
// 512 thr = 8 waves. KV tiles of 64 keys; T14 async-STAGE; triangle skip.
// LDS 45 KiB -> grid 96x8 = 768 blocks = exactly 3/CU.
// ---------------------------------------------------------------------------
__global__ __launch_bounds__(512) void attn_fwd(
    const u16* __restrict__ qk, const u16* __restrict__ vT, u16* __restrict__ y)
{
  const int bh = blockIdx.x;        // b*12 + h
  const int qt = 7 - blockIdx.y;    // reversed: long blocks dispatch first
  const int b = bh / 12, h = bh % 12;
  const long rowOff = (long)b * 1024;
  const int qb = qt * 128;

  __shared__ __align__(16) u16 sK[64 * 72];
  __shared__ __align__(16) u16 sV[2][64 * 72];  // V^T [d][key], double-buffered
  __shared__ __align__(16) u16 sP[128 * 72];    // P [qrow][key]

  const int tid = threadIdx.x;
  const int lane = tid & 63, wave = tid >> 6;   // 8 waves
  const int l15 = lane & 15, q = lane >> 4;
  const int qrow_l = wave * 16 + l15;           // local q-row 0..127
  const int qrow_g = qb + qrow_l;
  const int wave_max_row = qb + wave * 16 + 15; // wave-uniform

  const int sr = tid >> 3, sc = (tid & 7) * 8;
  const u16* kBase = qk + rowOff * 1536 + 768 + (long)h * 64;  // K rows, stride 1536
  const u16* vBase = vT + (long)bh * 65536;                    // V^T rows d, stride 1024

  short8 qf[2];
  {
    const u16* qp = qk + (long)(rowOff + qrow_g) * 1536 + h * 64 + q * 8;
    short8 a0 = *(const short8*)(qp);
    short8 a1 = *(const short8*)(qp + 32);
#pragma unroll
    for (int i = 0; i < 8; i++) {
      a0[i] = (short)f2b(b2f((u16)a0[i]) * 0.125f);
      a1[i] = (short)f2b(b2f((u16)a1[i]) * 0.125f);
    }
    qf[0] = a0; qf[1] = a1;
  }

  float m_i = -1e30f, l_i = 0.f;
  floatx4 o[4];
#pragma unroll
  for (int nt = 0; nt < 4; nt++) o[nt] = (floatx4){0.f, 0.f, 0.f, 0.f};

  const int J = 2 * qt + 1;   // last KV-tile index

  *(short8*)(sK + sr * 72 + sc)    = *(const short8*)(kBase + (long)sr * 1536 + sc);
  *(short8*)(sV[0] + sr * 72 + sc) = *(const short8*)(vBase + (long)sr * 1024 + sc);
  __syncthreads();

  for (int j = 0; j <= J; j++) {
    const int jb = j * 64;
    const bool active = (jb <= wave_max_row);   // wave-uniform triangle skip
    const u16* sVc = sV[j & 1];

    // T14: issue next tile's global loads NOW
    short8 rk = {}, rv = {};
    if (j < J) {
      rk = *(const short8*)(kBase + (long)(jb + 64 + sr) * 1536 + sc);
      rv = *(const short8*)(vBase + (long)sr * 1024 + (jb + 64) + sc);
    }

    float al = 1.f;
    if (active) {
      floatx4 sf[4];
#pragma unroll
      for (int mt = 0; mt < 4; mt++) sf[mt] = (floatx4){0.f, 0.f, 0.f, 0.f};
#pragma unroll
      for (int kk = 0; kk < 2; kk++) {
#pragma unroll
        for (int mt = 0; mt < 4; mt++) {
          short8 kf = *(const short8*)(sK + (mt * 16 + l15) * 72 + kk * 32 + q * 8);
          sf[mt] = __builtin_amdgcn_mfma_f32_16x16x32_bf16(kf, qf[kk], sf[mt], 0, 0, 0);
        }
      }

      float mx = m_i;
#pragma unroll
      for (int mt = 0; mt < 4; mt++)
#pragma unroll
        for (int r = 0; r < 4; r++) {
          int key_g = jb + mt * 16 + q * 4 + r;
          float v = sf[mt][r];
          if (key_g > qrow_g) v = -1e30f;
          sf[mt][r] = v;
          mx = fmaxf(mx, v);
        }
      mx = fmaxf(mx, __shfl_xor(mx, 16));
      mx = fmaxf(mx, __shfl_xor(mx, 32));
      al = __expf(m_i - mx);
      m_i = mx;
      float rsum = 0.f;
#pragma unroll
      for (int mt = 0; mt < 4; mt++) {
        short4v pv;
#pragma unroll
        for (int r = 0; r < 4; r++) {
          float p = __expf(sf[mt][r] - mx);
          rsum += p;
          pv[r] = (short)f2b(p);
        }
        *(short4v*)(sP + qrow_l * 72 + mt * 16 + q * 4) = pv;
      }
      rsum += __shfl_xor(rsum, 16);
      rsum += __shfl_xor(rsum, 32);
      l_i = l_i * al + rsum;
    }
    __syncthreads();   // sP visible; all QK reads of sK(j) done

    if (j < J) {
      *(short8*)(sK + sr * 72 + sc)              = rk;
      *(short8*)(sV[(j + 1) & 1] + sr * 72 + sc) = rv;
    }

    if (active) {
      float al_r[4];
#pragma unroll
      for (int r = 0; r < 4; r++) al_r[r] = __shfl(al, q * 4 + r);
#pragma unroll
      for (int nt = 0; nt < 4; nt++)
#pragma unroll
        for (int r = 0; r < 4; r++) o[nt][r] *= al_r[r];
#pragma unroll
      for (int kk = 0; kk < 2; kk++) {
        short8 pf = *(const short8*)(sP + qrow_l * 72 + kk * 32 + q * 8);
#pragma unroll
        for (int nt = 0; nt < 4; nt++) {
          short8 vf = *(const short8*)(sVc + (nt * 16 + l15) * 72 + kk * 32 + q * 8);
          o[nt] = __builtin_amdgcn_mfma_f32_16x16x32_bf16(pf, vf, o[nt], 0, 0, 0);
        }
      }
    }
    __syncthreads();   // sK(j+1)/sV writes done before QK(j+1); sP(j) reads done
  }

  float linv = 1.f / l_i;
  float li_r[4];
#pragma unroll
  for (int r = 0; r < 4; r++) li_r[r] = __shfl(linv, q * 4 + r);
#pragma unroll
  for (int nt = 0; nt < 4; nt++)
#pragma unroll
    for (int r = 0; r < 4; r++) {
      int row = qb + wave * 16 + q * 4 + r;
      int col = h * 64 + nt * 16 + l15;
      y[(rowOff + row) * 768 + col] = f2b(o[nt][r] * li_r[r]);
    }
}

// ---------------------------------------------------------------------------
extern "C" void kernel_launch(void* const* d_in, const int* in_sizes, int n_in,
                              void* d_out, int out_size, void* d_ws, size_t ws_size,
                              hipStream_t stream) {
  const float* x      = (const float*)d_in[0];  // [8192][768] fp32
  const float* w_attn = (const float*)d_in[1];  // [768][2304] fp32
  const float* b_attn = (const float*)d_in[2];  // [2304] fp32
  const float* w_proj = (const float*)d_in[3];  // [768][768] fp32
  const float* b_proj = (const float*)d_in[4];  // [768] fp32
  float* out = (float*)d_out;                   // [8192][768] fp32

  char* ws = (char*)d_ws;
  u16* xb   = (u16*)ws; ws += (size_t)8192 * 768 * 2;     // 12.6 MB
  u16* wTa  = (u16*)ws; ws += (size_t)2304 * 768 * 2;     //  3.5 MB
  u16* wTp  = (u16*)ws; ws += (size_t)768 * 768 * 2;      //  1.2 MB
  u16* qk   = (u16*)ws; ws += (size_t)8192 * 1536 * 2;    // 25.2 MB (Q|K)
  u16* vT   = (u16*)ws; ws += (size_t)96 * 64 * 1024 * 2; // 12.6 MB (V^T)
  u16* yatt = (u16*)ws; ws += (size_t)8192 * 768 * 2;     // 12.6 MB

  // fused prep: x->bf16 + both weight transposes
  prep<<<dim3(6720), 256, 0, stream>>>(x, xb, w_attn, wTa, w_proj, wTp);

  // qkv GEMM: 128x288 tiles, grid 512 = exactly 2 blocks/CU co-resident
  gemm_pipe<u16, 288, true><<<dim3(512), 384, 0, stream>>>(
      xb, wTa, b_attn, qk, vT, 1536);

  // flash attention: 128-row Q-tiles, 8 waves, async-staged K/V
  attn_fwd<<<dim3(96, 8), 512, 0, stream>>>(qk, vT, yatt);

  // proj GEMM: 128x96 tiles, grid 512 = 2 blocks/CU, fp32 out
  gemm_pipe<float, 96, false><<<dim3(512), 384, 0, stream>>>(
      yatt, wTp, b_proj, out, (u16*)nullptr, 768);
}

// Round 6
// 195.736 us; speedup vs baseline: 1.1878x; 1.1878x over previous
//
#include <hip/hip_runtime.h>
#include <hip/hip_bf16.h>
#include <stdint.h>

typedef unsigned short u16;
typedef short short8 __attribute__((ext_vector_type(8)));
typedef short short4v __attribute__((ext_vector_type(4)));
typedef float floatx4 __attribute__((ext_vector_type(4)));

__device__ __forceinline__ float b2f(u16 v) {
  union { unsigned int u; float f; } c; c.u = ((unsigned int)v) << 16; return c.f;
}
__device__ __forceinline__ u16 f2b(float f) {
  union { float f; unsigned int u; } c; c.f = f;
  unsigned int u = c.u;
  return (u16)((u + 0x7fffu + ((u >> 16) & 1u)) >> 16);  // RNE
}

// async global->LDS, 16B per lane. LDS dest must be wave-uniform base + lane*16.
__device__ __forceinline__ void gld_lds16(const u16* g, u16* l) {
  __builtin_amdgcn_global_load_lds(
      (const __attribute__((address_space(1))) unsigned int*)g,
      (__attribute__((address_space(3))) unsigned int*)l,
      16, 0, 0);
}

// ---------------------------------------------------------------------------
// Fused prep: x fp32->bf16 (blocks 0..6143), w_attn T (6144..6575),
// w_proj T (6576..6719). Transposes also convert fp32->bf16.
// ---------------------------------------------------------------------------
__device__ __forceinline__ void tile_transpose_f2b(
    const float* __restrict__ in, u16* __restrict__ out,
    int inRS, int outRS, int rb, int cb, int tid)
{
  __shared__ __align__(16) u16 t[64][72];
  const int r = tid >> 2, sg = tid & 3;
  const float* ip = in + (long)(rb + r) * inRS + cb + sg * 16;
#pragma unroll
  for (int i = 0; i < 16; i += 4) {
    float4 f = *(const float4*)(ip + i);
    t[r][sg * 16 + i]     = f2b(f.x);
    t[r][sg * 16 + i + 1] = f2b(f.y);
    t[r][sg * 16 + i + 2] = f2b(f.z);
    t[r][sg * 16 + i + 3] = f2b(f.w);
  }
  __syncthreads();
  short8 v0, v1;
#pragma unroll
  for (int i = 0; i < 8; i++) v0[i] = (short)t[sg * 16 + i][r];
#pragma unroll
  for (int i = 0; i < 8; i++) v1[i] = (short)t[sg * 16 + 8 + i][r];
  *(short8*)(out + (long)(cb + r) * outRS + rb + sg * 16)     = v0;
  *(short8*)(out + (long)(cb + r) * outRS + rb + sg * 16 + 8) = v1;
}

__global__ __launch_bounds__(256) void prep(
    const float* __restrict__ x, u16* __restrict__ xb,
    const float* __restrict__ w_attn, u16* __restrict__ wTa,
    const float* __restrict__ w_proj, u16* __restrict__ wTp)
{
  const int bid = blockIdx.x, tid = threadIdx.x;
  if (bid < 6144) {
    int i = (bid * 256 + tid) * 4;
    float4 f = *(const float4*)(x + i);
    short4v v;
    v[0] = (short)f2b(f.x); v[1] = (short)f2b(f.y);
    v[2] = (short)f2b(f.z); v[3] = (short)f2b(f.w);
    *(short4v*)(xb + i) = v;
  } else if (bid < 6576) {
    int t = bid - 6144;                 // 36 x 12 tiles of w_attn [768][2304]
    tile_transpose_f2b(w_attn, wTa, 2304, 768, (t / 36) * 64, (t % 36) * 64, tid);
  } else {
    int t = bid - 6576;                 // 12 x 12 tiles of w_proj [768][768]
    tile_transpose_f2b(w_proj, wTp, 768, 768, (t / 12) * 64, (t % 12) * 64, tid);
  }
}

// ---------------------------------------------------------------------------
// Legacy C = A * Bt^T + bias (proj GEMM, 128x128 tiles — known-good R11 cfg).
// ---------------------------------------------------------------------------
__device__ __forceinline__ void store_out(u16* p, float v)  { *p = f2b(v); }
__device__ __forceinline__ void store_out(float* p, float v) { *p = v; }

template <int BM>
__device__ __forceinline__ void stage(
    const u16* __restrict__ A, const u16* __restrict__ Bt,
    long rowbase, long colbase, int K, int k0,
    u16* dA, u16* dB, int tid)
{
  const int c0 = tid, c1 = tid + 256;
  const int ar0 = c0 >> 2, ak0 = (c0 & 3) * 8;
  const int ar1 = c1 >> 2, ak1 = (c1 & 3) * 8;
  gld_lds16(A + (rowbase + ar0) * K + k0 + ak0, dA + c0 * 8);
  if (BM == 128)
    gld_lds16(A + (rowbase + ar1) * K + k0 + ak1, dA + c1 * 8);
  gld_lds16(Bt + (colbase + ar0) * K + k0 + ak0, dB + c0 * 8);
  gld_lds16(Bt + (colbase + ar1) * K + k0 + ak1, dB + c1 * 8);
}

template <typename OT, int BM, bool SPLIT>
__global__ __launch_bounds__(256) void gemm_bt_bias(
    const u16* __restrict__ A, const u16* __restrict__ Bt,
    const float* __restrict__ bias, OT* __restrict__ C, u16* __restrict__ vT,
    int M, int N, int K, int strideC)
{
  constexpr int WNF = (BM == 128) ? 4 : 2;      // n-frags per wave
  __shared__ __align__(16) u16 sA[2][BM * 32];
  __shared__ __align__(16) u16 sB[2][128 * 32];
  const int tid = threadIdx.x;
  const int lane = tid & 63;
  const int wave = tid >> 6;
  const int wm = (BM == 128) ? (wave >> 1) * 64 : 0;
  const int wn = (BM == 128) ? (wave & 1) * 64 : wave * 32;
  const int l15 = lane & 15;
  const int q = lane >> 4;
  const long rowbase = (long)blockIdx.y * BM;
  const long colbase = (long)blockIdx.x * 128;

  floatx4 acc[4][WNF];
#pragma unroll
  for (int i = 0; i < 4; i++)
#pragma unroll
    for (int j = 0; j < WNF; j++) acc[i][j] = (floatx4){0.f, 0.f, 0.f, 0.f};

  stage<BM>(A, Bt, rowbase, colbase, K, 0, sA[0], sB[0], tid);
  __syncthreads();   // buf0 ready

  const int NIT = K / 32;
  for (int it = 0; it < NIT; ++it) {
    const int cur = it & 1;
    if (it + 1 < NIT)
      stage<BM>(A, Bt, rowbase, colbase, K, (it + 1) * 32, sA[cur ^ 1], sB[cur ^ 1], tid);
    short8 af[4], bf[WNF];
#pragma unroll
    for (int mt = 0; mt < 4; mt++)
      af[mt] = *(const short8*)(sA[cur] + (wm + mt * 16 + l15) * 32 + q * 8);
#pragma unroll
    for (int nt = 0; nt < WNF; nt++)
      bf[nt] = *(const short8*)(sB[cur] + (wn + nt * 16 + l15) * 32 + q * 8);
#pragma unroll
    for (int mt = 0; mt < 4; mt++)
#pragma unroll
      for (int nt = 0; nt < WNF; nt++)
        acc[mt][nt] = __builtin_amdgcn_mfma_f32_16x16x32_bf16(af[mt], bf[nt], acc[mt][nt], 0, 0, 0);
    if (it + 1 < NIT) __syncthreads();
  }

  if (SPLIT && colbase >= 1536) {
    const long b = rowbase >> 10;
    const int t0b = (int)(rowbase & 1023) + wm;
#pragma unroll
    for (int nt = 0; nt < WNF; nt++) {
      const int col = (int)colbase + wn + nt * 16 + l15;
      const float bv = bias[col];
      const int dloc = col - 1536;
      u16* bp = vT + (b * 12 + (dloc >> 6)) * 65536L + (long)(dloc & 63) * 1024;
#pragma unroll
      for (int mt = 0; mt < 4; mt++) {
        short4v pv;
#pragma unroll
        for (int r = 0; r < 4; r++) pv[r] = (short)f2b(acc[mt][nt][r] + bv);
        *(short4v*)(bp + t0b + mt * 16 + q * 4) = pv;
      }
    }
  } else {
#pragma unroll
    for (int nt = 0; nt < WNF; nt++) {
      const long col = colbase + wn + nt * 16 + l15;
      const float bv = bias[col];
#pragma unroll
      for (int mt = 0; mt < 4; mt++)
#pragma unroll
        for (int r = 0; r < 4; r++) {
          const long row = rowbase + wm + mt * 16 + q * 4 + r;
          store_out(C + row * strideC + col, acc[mt][nt][r] + bv);
        }
    }
  }
}

// ---------------------------------------------------------------------------
// R13 qkv GEMM: R10 shell (256x288, BK=32, 4 slots, 12 waves, grid 256 =
// 1 block/CU, XCD swizzle, 0-conflict LDS swizzle, counted vmcnt) + the
// m201 FINE-PHASE discipline that R9-R12's 2-fat-phase structure lacked:
// per slot, 2 phases of {ds_reads -> stage half of tile j+3 -> s_barrier ->
// setprio(1) 12-MFMA cluster -> setprio(0) -> s_barrier}. Boundary vmcnt
// (wave-uniform 8/6/4; never 0 mid-loop) folded into phase-1's pre-MFMA
// barrier: all waves' tile-(j+1) loads resident once the barrier clears.
//
// Slot safety: stage into slot (j+3)&3 = (j-1)&3; its last reads were in
// tile j-1's phases, completed before tile j-1's final barrier; STAGE(j+3)
// issues after it.  Falsifier: dur >= 45us -> m201 discipline does not
// transfer to K=768 and we revert to R11 qkv.
// ---------------------------------------------------------------------------
#define QKV_K 768
#define QKV_NT 24   // 768/32
#define VMW(n) asm volatile("s_waitcnt vmcnt(" #n ")" ::: "memory")

__global__ __launch_bounds__(768, 3) void gemm_qkv_8ph(
    const u16* __restrict__ A, const u16* __restrict__ Bt,
    const float* __restrict__ bias, u16* __restrict__ qkOut, u16* __restrict__ vT)
{
  __shared__ __align__(16) u16 sA[4][256 * 32];   // 64 KiB
  __shared__ __align__(16) u16 sB[4][288 * 32];   // 72 KiB

  const int bid = blockIdx.x;
  const int wg = (bid & 7) * 32 + (bid >> 3);   // XCD-contiguous
  const int bx = wg & 7;        // col tile 0..7 (288 cols each)
  const int by = wg >> 3;       // row tile 0..31 (256 rows each)

  const int tid = threadIdx.x;
  const int lane = tid & 63;
  const int l15 = lane & 15, q = lane >> 4;
  const int wave = tid >> 6;          // 0..11
  const int wm = (wave / 6) * 128;    // 2 M-groups
  const int wn = (wave % 6) * 48;     // 6 N-groups (3 frags each)
  const long rowbase = (long)by * 256;
  const long colbase = (long)bx * 288;
  const int xq = ((q ^ ((l15 >> 1) & 3)) << 3);   // swizzled k-octet (u16)

  // staging chunk c (16B): LDS row = c>>2, octet = c&3;
  // pre-swizzled global octet = (c&3)^((c>>3)&3)
  const int cA0 = tid, cA1 = 768 + tid;   // A: 1024 chunks
  const int cB0 = tid, cB1 = 768 + tid;   // B: 1152 chunks
  const u16* pa0 = A + (rowbase + (cA0 >> 2)) * QKV_K + ((((cA0 & 3) ^ ((cA0 >> 3) & 3))) << 3);
  const u16* pa1 = A + (rowbase + (cA1 >> 2)) * QKV_K + ((((cA1 & 3) ^ ((cA1 >> 3) & 3))) << 3);
  const u16* pb0 = Bt + (colbase + (cB0 >> 2)) * QKV_K + ((((cB0 & 3) ^ ((cB0 >> 3) & 3))) << 3);
  const u16* pb1 = Bt + (colbase + (cB1 >> 2)) * QKV_K + ((((cB1 & 3) ^ ((cB1 >> 3) & 3))) << 3);
  const bool hasA1 = (tid < 256);   // wave-uniform (waves 0-3)
  const bool hasB1 = (tid < 384);   // wave-uniform (waves 0-5)

#define STAGE_A(t, s) do { const long k0_ = (long)(t) * 32; \
    gld_lds16(pa0 + k0_, &sA[s][cA0 * 8]); \
    if (hasA1) gld_lds16(pa1 + k0_, &sA[s][cA1 * 8]); } while (0)
#define STAGE_B(t, s) do { const long k0_ = (long)(t) * 32; \
    gld_lds16(pb0 + k0_, &sB[s][cB0 * 8]); \
    if (hasB1) gld_lds16(pb1 + k0_, &sB[s][cB1 * 8]); } while (0)
  // per-slot issues: waves 0-3: 4, waves 4-5: 3, waves 6-11: 2
#define WAIT2() do { if (wave < 4) { VMW(8); } else if (wave < 6) { VMW(6); } else { VMW(4); } } while (0)
#define WAIT1() do { if (wave < 4) { VMW(4); } else if (wave < 6) { VMW(3); } else { VMW(2); } } while (0)

  floatx4 acc[8][3];
#pragma unroll
  for (int i = 0; i < 8; i++)
#pragma unroll
    for (int n = 0; n < 3; n++) acc[i][n] = (floatx4){0.f, 0.f, 0.f, 0.f};

  // prologue: tiles 0,1,2 -> slots 0,1,2; wait own tile-0 loads
  STAGE_A(0, 0); STAGE_B(0, 0);
  STAGE_A(1, 1); STAGE_B(1, 1);
  STAGE_A(2, 2); STAGE_B(2, 2);
  WAIT2();
  __builtin_amdgcn_s_barrier();   // all waves' tile-0 resident

#pragma unroll 4
  for (int j = 0; j < QKV_NT; ++j) {
    const int slot = j & 3;
    const u16* ap = sA[slot];
    const u16* bp = sB[slot];

    // ======== phase 0: 7 ds_reads, stage A(j+3), barrier, 12 MFMA ========
    short8 bf[3], af[4];
#pragma unroll
    for (int nt = 0; nt < 3; nt++)
      bf[nt] = *(const short8*)(bp + (wn + nt * 16 + l15) * 32 + xq);
#pragma unroll
    for (int mt = 0; mt < 4; mt++)
      af[mt] = *(const short8*)(ap + (wm + mt * 16 + l15) * 32 + xq);
    if (j + 3 < QKV_NT) STAGE_A(j + 3, (j + 3) & 3);
    __builtin_amdgcn_s_barrier();
    __builtin_amdgcn_s_setprio(1);
#pragma unroll
    for (int mt = 0; mt < 4; mt++)
#pragma unroll
      for (int nt = 0; nt < 3; nt++)
        acc[mt][nt] = __builtin_amdgcn_mfma_f32_16x16x32_bf16(af[mt], bf[nt], acc[mt][nt], 0, 0, 0);
    __builtin_amdgcn_s_setprio(0);
    __builtin_amdgcn_s_barrier();

    // ======== phase 1: 4 ds_reads, stage B(j+3), vmcnt+barrier, 12 MFMA ====
#pragma unroll
    for (int mt = 0; mt < 4; mt++)
      af[mt] = *(const short8*)(ap + (wm + 64 + mt * 16 + l15) * 32 + xq);
    if (j + 3 < QKV_NT) STAGE_B(j + 3, (j + 3) & 3);
    if (j < QKV_NT - 1) {
      if (j + 3 < QKV_NT)      WAIT2();   // leave tiles j+2, j+3 in flight
      else if (j + 2 < QKV_NT) WAIT1();   // leave tile j+2 in flight
      else                     VMW(0);    // tail
    }
    __builtin_amdgcn_s_barrier();
    __builtin_amdgcn_s_setprio(1);
#pragma unroll
    for (int mt = 0; mt < 4; mt++)
#pragma unroll
      for (int nt = 0; nt < 3; nt++)
        acc[4 + mt][nt] = __builtin_amdgcn_mfma_f32_16x16x32_bf16(af[mt], bf[nt], acc[4 + mt][nt], 0, 0, 0);
    __builtin_amdgcn_s_setprio(0);
    __builtin_amdgcn_s_barrier();
  }
#undef STAGE_A
#undef STAGE_B
#undef WAIT2
#undef WAIT1

  // ---- epilogue: per-fragment split at col 1536 (16-aligned inside bx=5) ----
#pragma unroll
  for (int nt = 0; nt < 3; nt++) {
    const int fragc = (int)colbase + wn + nt * 16;   // lane-invariant, 16-aligned
    const int col = fragc + l15;
    const float bv = bias[col];
    if (fragc >= 1536) {
      const long bb = rowbase >> 10;
      const int dloc = col - 1536;
      u16* op = vT + (bb * 12 + (dloc >> 6)) * 65536L + (long)(dloc & 63) * 1024;
      const int t0 = (int)(rowbase & 1023) + wm;
#pragma unroll
      for (int mt = 0; mt < 8; mt++) {
        short4v pv;
#pragma unroll
        for (int r = 0; r < 4; r++) pv[r] = (short)f2b(acc[mt][nt][r] + bv);
        *(short4v*)(op + t0 + mt * 16 + q * 4) = pv;
      }
    } else {
#pragma unroll
      for (int mt = 0; mt < 8; mt++)
#pragma unroll
        for (int r = 0; r < 4; r++) {
          const long row = rowbase + wm + mt * 16 + q * 4 + r;
          qkOut[row * 1536 + col] = f2b(acc[mt][nt][r] + bv);
        }
    }
  }
}
#undef VMW

// ---------------------------------------------------------------------------
// Flash attention, causal (R11 version, unchanged). One block = (b*12+h,
// 128 q-rows), 512 thr = 8 waves. KV tiles of 64 keys; T14 async-STAGE;
// wave-uniform triangle skip. LDS 45 KiB -> grid 96x8 = 768 blocks = 3/CU.
// ---------------------------------------------------------------------------
__global__ __launch_bounds__(512) void attn_fwd(
    const u16* __restrict__ qk, const u16* __restrict__ vT, u16* __restrict__ y)
{
  const int bh = blockIdx.x;        // b*12 + h
  const int qt = 7 - blockIdx.y;    // reversed: long blocks dispatch first
  const int b = bh / 12, h = bh % 12;
  const long rowOff = (long)b * 1024;
  const int qb = qt * 128;

  __shared__ __align__(16) u16 sK[64 * 72];
  __shared__ __align__(16) u16 sV[2][64 * 72];  // V^T [d][key], double-buffered
  __shared__ __align__(16) u16 sP[128 * 72];    // P [qrow][key]

  const int tid = threadIdx.x;
  const int lane = tid & 63, wave = tid >> 6;   // 8 waves
  const int l15 = lane & 15, q = lane >> 4;
  const int qrow_l = wave * 16 + l15;           // local q-row 0..127
  const int qrow_g = qb + qrow_l;
  const int wave_max_row = qb + wave * 16 + 15; // wave-uniform

  const int sr = tid >> 3, sc = (tid & 7) * 8;
  const u16* kBase = qk + rowOff * 1536 + 768 + (long)h * 64;  // K rows, stride 1536
  const u16* vBase = vT + (long)bh * 65536;                    // V^T rows d, stride 1024

  short8 qf[2];
  {
    const u16* qp = qk + (long)(rowOff + qrow_g) * 1536 + h * 64 + q * 8;
    short8 a0 = *(const short8*)(qp);
    short8 a1 = *(const short8*)(qp + 32);
#pragma unroll
    for (int i = 0; i < 8; i++) {
      a0[i] = (short)f2b(b2f((u16)a0[i]) * 0.125f);
      a1[i] = (short)f2b(b2f((u16)a1[i]) * 0.125f);
    }
    qf[0] = a0; qf[1] = a1;
  }

  float m_i = -1e30f, l_i = 0.f;
  floatx4 o[4];
#pragma unroll
  for (int nt = 0; nt < 4; nt++) o[nt] = (floatx4){0.f, 0.f, 0.f, 0.f};

  const int J = 2 * qt + 1;   // last KV-tile index

  *(short8*)(sK + sr * 72 + sc)    = *(const short8*)(kBase + (long)sr * 1536 + sc);
  *(short8*)(sV[0] + sr * 72 + sc) = *(const short8*)(vBase + (long)sr * 1024 + sc);
  __syncthreads();

  for (int j = 0; j <= J; j++) {
    const int jb = j * 64;
    const bool active = (jb <= wave_max_row);   // wave-uniform triangle skip
    const u16* sVc = sV[j & 1];

    // T14: issue next tile's global loads NOW
    short8 rk = {}, rv = {};
    if (j < J) {
      rk = *(const short8*)(kBase + (long)(jb + 64 + sr) * 1536 + sc);
      rv = *(const short8*)(vBase + (long)sr * 1024 + (jb + 64) + sc);
    }

    float al = 1.f;
    if (active) {
      floatx4 sf[4];
#pragma unroll
      for (int mt = 0; mt < 4; mt++) sf[mt] = (floatx4){0.f, 0.f, 0.f, 0.f};
#pragma unroll
      for (int kk = 0; kk < 2; kk++) {
#pragma unroll
        for (int mt = 0; mt < 4; mt++) {
          short8 kf = *(const short8*)(sK + (mt * 16 + l15) * 72 + kk * 32 + q * 8);
          sf[mt] = __builtin_amdgcn_mfma_f32_16x16x32_bf16(kf, qf[kk], sf[mt], 0, 0, 0);
        }
      }

      float mx = m_i;
#pragma unroll
      for (int mt = 0; mt < 4; mt++)
#pragma unroll
        for (int r = 0; r < 4; r++) {
          int key_g = jb + mt * 16 + q * 4 + r;
          float v = sf[mt][r];
          if (key_g > qrow_g) v = -1e30f;
          sf[mt][r] = v;
          mx = fmaxf(mx, v);
        }
      mx = fmaxf(mx, __shfl_xor(mx, 16));
      mx = fmaxf(mx, __shfl_xor(mx, 32));
      al = __expf(m_i - mx);
      m_i = mx;
      float rsum = 0.f;
#pragma unroll
      for (int mt = 0; mt < 4; mt++) {
        short4v pv;
#pragma unroll
        for (int r = 0; r < 4; r++) {
          float p = __expf(sf[mt][r] - mx);
          rsum += p;
          pv[r] = (short)f2b(p);
        }
        *(short4v*)(sP + qrow_l * 72 + mt * 16 + q * 4) = pv;
      }
      rsum += __shfl_xor(rsum, 16);
      rsum += __shfl_xor(rsum, 32);
      l_i = l_i * al + rsum;
    }
    __syncthreads();   // sP visible; all QK reads of sK(j) done

    if (j < J) {
      *(short8*)(sK + sr * 72 + sc)              = rk;
      *(short8*)(sV[(j + 1) & 1] + sr * 72 + sc) = rv;
    }

    if (active) {
      float al_r[4];
#pragma unroll
      for (int r = 0; r < 4; r++) al_r[r] = __shfl(al, q * 4 + r);
#pragma unroll
      for (int nt = 0; nt < 4; nt++)
#pragma unroll
        for (int r = 0; r < 4; r++) o[nt][r] *= al_r[r];
#pragma unroll
      for (int kk = 0; kk < 2; kk++) {
        short8 pf = *(const short8*)(sP + qrow_l * 72 + kk * 32 + q * 8);
#pragma unroll
        for (int nt = 0; nt < 4; nt++) {
          short8 vf = *(const short8*)(sVc + (nt * 16 + l15) * 72 + kk * 32 + q * 8);
          o[nt] = __builtin_amdgcn_mfma_f32_16x16x32_bf16(pf, vf, o[nt], 0, 0, 0);
        }
      }
    }
    __syncthreads();   // sK(j+1)/sV writes done before QK(j+1); sP(j) reads done
  }

  float linv = 1.f / l_i;
  float li_r[4];
#pragma unroll
  for (int r = 0; r < 4; r++) li_r[r] = __shfl(linv, q * 4 + r);
#pragma unroll
  for (int nt = 0; nt < 4; nt++)
#pragma unroll
    for (int r = 0; r < 4; r++) {
      int row = qb + wave * 16 + q * 4 + r;
      int col = h * 64 + nt * 16 + l15;
      y[(rowOff + row) * 768 + col] = f2b(o[nt][r] * li_r[r]);
    }
}

// ---------------------------------------------------------------------------
extern "C" void kernel_launch(void* const* d_in, const int* in_sizes, int n_in,
                              void* d_out, int out_size, void* d_ws, size_t ws_size,
                              hipStream_t stream) {
  const float* x      = (const float*)d_in[0];  // [8192][768] fp32
  const float* w_attn = (const float*)d_in[1];  // [768][2304] fp32
  const float* b_attn = (const float*)d_in[2];  // [2304] fp32
  const float* w_proj = (const float*)d_in[3];  // [768][768] fp32
  const float* b_proj = (const float*)d_in[4];  // [768] fp32
  float* out = (float*)d_out;                   // [8192][768] fp32

  char* ws = (char*)d_ws;
  u16* xb   = (u16*)ws; ws += (size_t)8192 * 768 * 2;     // 12.6 MB
  u16* wTa  = (u16*)ws; ws += (size_t)2304 * 768 * 2;     //  3.5 MB
  u16* wTp  = (u16*)ws; ws += (size_t)768 * 768 * 2;      //  1.2 MB
  u16* qk   = (u16*)ws; ws += (size_t)8192 * 1536 * 2;    // 25.2 MB (Q|K)
  u16* vT   = (u16*)ws; ws += (size_t)96 * 64 * 1024 * 2; // 12.6 MB (V^T)
  u16* yatt = (u16*)ws; ws += (size_t)8192 * 768 * 2;     // 12.6 MB

  // fused prep: x->bf16 + both weight transposes
  prep<<<dim3(6720), 256, 0, stream>>>(x, xb, w_attn, wTa, w_proj, wTp);

  // qkv GEMM: 256x288 tiles, grid 256 = 1 block/CU, m201 fine-phase schedule
  gemm_qkv_8ph<<<dim3(256), 768, 0, stream>>>(xb, wTa, b_attn, qk, vT);

  // flash attention: 128-row Q-tiles, 8 waves, async-staged K/V
  attn_fwd<<<dim3(96, 8), 512, 0, stream>>>(qk, vT, yatt);

  // out = yatt @ w_proj + b_proj   (fp32 out, 128x128 tiles — R11 known-good)
  gemm_bt_bias<float, 128, false><<<dim3(6, 64), 256, 0, stream>>>(
      yatt, wTp, b_proj, out, (u16*)nullptr, 8192, 768, 768, 768);
}

// Round 7
// 189.345 us; speedup vs baseline: 1.2279x; 1.0338x over previous
//
#include <hip/hip_runtime.h>
#include <hip/hip_bf16.h>
#include <stdint.h>

typedef unsigned short u16;
typedef short short8 __attribute__((ext_vector_type(8)));
typedef short short4v __attribute__((ext_vector_type(4)));
typedef float floatx4 __attribute__((ext_vector_type(4)));

__device__ __forceinline__ float b2f(u16 v) {
  union { unsigned int u; float f; } c; c.u = ((unsigned int)v) << 16; return c.f;
}
__device__ __forceinline__ u16 f2b(float f) {
  union { float f; unsigned int u; } c; c.f = f;
  unsigned int u = c.u;
  return (u16)((u + 0x7fffu + ((u >> 16) & 1u)) >> 16);  // RNE
}

// async global->LDS, 16B per lane. LDS dest must be wave-uniform base + lane*16.
__device__ __forceinline__ void gld_lds16(const u16* g, u16* l) {
  __builtin_amdgcn_global_load_lds(
      (const __attribute__((address_space(1))) unsigned int*)g,
      (__attribute__((address_space(3))) unsigned int*)l,
      16, 0, 0);
}

// ---------------------------------------------------------------------------
// Fused prep: x fp32->bf16 (blocks 0..6143), w_attn T (6144..6575),
// w_proj T (6576..6719). Transposes also convert fp32->bf16.
// ---------------------------------------------------------------------------
__device__ __forceinline__ void tile_transpose_f2b(
    const float* __restrict__ in, u16* __restrict__ out,
    int inRS, int outRS, int rb, int cb, int tid)
{
  __shared__ __align__(16) u16 t[64][72];
  const int r = tid >> 2, sg = tid & 3;
  const float* ip = in + (long)(rb + r) * inRS + cb + sg * 16;
#pragma unroll
  for (int i = 0; i < 16; i += 4) {
    float4 f = *(const float4*)(ip + i);
    t[r][sg * 16 + i]     = f2b(f.x);
    t[r][sg * 16 + i + 1] = f2b(f.y);
    t[r][sg * 16 + i + 2] = f2b(f.z);
    t[r][sg * 16 + i + 3] = f2b(f.w);
  }
  __syncthreads();
  short8 v0, v1;
#pragma unroll
  for (int i = 0; i < 8; i++) v0[i] = (short)t[sg * 16 + i][r];
#pragma unroll
  for (int i = 0; i < 8; i++) v1[i] = (short)t[sg * 16 + 8 + i][r];
  *(short8*)(out + (long)(cb + r) * outRS + rb + sg * 16)     = v0;
  *(short8*)(out + (long)(cb + r) * outRS + rb + sg * 16 + 8) = v1;
}

__global__ __launch_bounds__(256) void prep(
    const float* __restrict__ x, u16* __restrict__ xb,
    const float* __restrict__ w_attn, u16* __restrict__ wTa,
    const float* __restrict__ w_proj, u16* __restrict__ wTp)
{
  const int bid = blockIdx.x, tid = threadIdx.x;
  if (bid < 6144) {
    int i = (bid * 256 + tid) * 4;
    float4 f = *(const float4*)(x + i);
    short4v v;
    v[0] = (short)f2b(f.x); v[1] = (short)f2b(f.y);
    v[2] = (short)f2b(f.z); v[3] = (short)f2b(f.w);
    *(short4v*)(xb + i) = v;
  } else if (bid < 6576) {
    int t = bid - 6144;                 // 36 x 12 tiles of w_attn [768][2304]
    tile_transpose_f2b(w_attn, wTa, 2304, 768, (t / 36) * 64, (t % 36) * 64, tid);
  } else {
    int t = bid - 6576;                 // 12 x 12 tiles of w_proj [768][768]
    tile_transpose_f2b(w_proj, wTp, 768, 768, (t / 12) * 64, (t % 12) * 64, tid);
  }
}

// ---------------------------------------------------------------------------
// qkv GEMM — R11 version VERBATIM (measured 45.5 us, twice).
// Tile 256x288, BK=32, 4 LDS slots, 768 thr = 12 waves (2M x 6N), grid 256
// = 1 block/CU. Distance-3 prefetch, counted wave-uniform vmcnt (8/6/4),
// ONE barrier per K-tile, setprio MFMA clusters, 0-conflict LDS swizzle.
// ---------------------------------------------------------------------------
#define QKV_K 768
#define QKV_NT 24   // 768/32
#define VMW(n) asm volatile("s_waitcnt vmcnt(" #n ")" ::: "memory")

__global__ __launch_bounds__(768, 3) void gemm_qkv_288(
    const u16* __restrict__ A, const u16* __restrict__ Bt,
    const float* __restrict__ bias, u16* __restrict__ qkOut, u16* __restrict__ vT)
{
  __shared__ __align__(16) u16 sA[4][256 * 32];   // 64 KiB
  __shared__ __align__(16) u16 sB[4][288 * 32];   // 72 KiB

  const int bid = blockIdx.x;
  const int wg = (bid & 7) * 32 + (bid >> 3);
  const int bx = wg & 7;        // col tile 0..7 (288 cols each)
  const int by = wg >> 3;       // row tile 0..31 (256 rows each)

  const int tid = threadIdx.x;
  const int lane = tid & 63;
  const int l15 = lane & 15, q = lane >> 4;
  const int wave = tid >> 6;          // 0..11
  const int wm = (wave / 6) * 128;    // 2 M-groups
  const int wn = (wave % 6) * 48;     // 6 N-groups (3 frags each)
  const long rowbase = (long)by * 256;
  const long colbase = (long)bx * 288;
  const int xq = ((q ^ ((l15 >> 1) & 3)) << 3);   // swizzled k-octet (u16)

  const int cA0 = tid, cA1 = 768 + tid;   // A: 1024 chunks (waves 0-3 take 2nd)
  const int cB0 = tid, cB1 = 768 + tid;   // B: 1152 chunks (waves 0-5 take 2nd)
  const u16* pa0 = A + (rowbase + (cA0 >> 2)) * QKV_K + ((((cA0 & 3) ^ ((cA0 >> 3) & 3))) << 3);
  const u16* pa1 = A + (rowbase + (cA1 >> 2)) * QKV_K + ((((cA1 & 3) ^ ((cA1 >> 3) & 3))) << 3);
  const u16* pb0 = Bt + (colbase + (cB0 >> 2)) * QKV_K + ((((cB0 & 3) ^ ((cB0 >> 3) & 3))) << 3);
  const u16* pb1 = Bt + (colbase + (cB1 >> 2)) * QKV_K + ((((cB1 & 3) ^ ((cB1 >> 3) & 3))) << 3);
  const bool hasA1 = (tid < 256);   // wave-uniform (waves 0-3)
  const bool hasB1 = (tid < 384);   // wave-uniform (waves 0-5)

#define STAGE(t, s) do { \
    const long k0_ = (long)(t) * 32; \
    gld_lds16(pa0 + k0_, &sA[s][cA0 * 8]); \
    if (hasA1) gld_lds16(pa1 + k0_, &sA[s][cA1 * 8]); \
    gld_lds16(pb0 + k0_, &sB[s][cB0 * 8]); \
    if (hasB1) gld_lds16(pb1 + k0_, &sB[s][cB1 * 8]); } while (0)

  floatx4 acc[8][3];
#pragma unroll
  for (int i = 0; i < 8; i++)
#pragma unroll
    for (int n = 0; n < 3; n++) acc[i][n] = (floatx4){0.f, 0.f, 0.f, 0.f};

  STAGE(0, 0); STAGE(1, 1); STAGE(2, 2);
  if (wave < 4) VMW(8); else if (wave < 6) VMW(6); else VMW(4);
  __builtin_amdgcn_s_barrier();   // all waves' tile-0 resident

#pragma unroll 4
  for (int j = 0; j < QKV_NT; ++j) {
    const int slot = j & 3;
    const u16* ap = sA[slot];
    const u16* bp = sB[slot];

    // phase A: 7 ds_reads, stage tile j+3, 12 MFMA
    short8 bf[3];
#pragma unroll
    for (int nt = 0; nt < 3; nt++)
      bf[nt] = *(const short8*)(bp + (wn + nt * 16 + l15) * 32 + xq);
    short8 af[4];
#pragma unroll
    for (int mt = 0; mt < 4; mt++)
      af[mt] = *(const short8*)(ap + (wm + mt * 16 + l15) * 32 + xq);
    if (j + 3 < QKV_NT) STAGE(j + 3, (j + 3) & 3);
    __builtin_amdgcn_s_setprio(1);
#pragma unroll
    for (int mt = 0; mt < 4; mt++)
#pragma unroll
      for (int nt = 0; nt < 3; nt++)
        acc[mt][nt] = __builtin_amdgcn_mfma_f32_16x16x32_bf16(af[mt], bf[nt], acc[mt][nt], 0, 0, 0);
    __builtin_amdgcn_s_setprio(0);

    // phase B: 4 ds_reads, 12 MFMA
#pragma unroll
    for (int mt = 0; mt < 4; mt++)
      af[mt] = *(const short8*)(ap + (wm + 64 + mt * 16 + l15) * 32 + xq);
    __builtin_amdgcn_s_setprio(1);
#pragma unroll
    for (int mt = 0; mt < 4; mt++)
#pragma unroll
      for (int nt = 0; nt < 3; nt++)
        acc[4 + mt][nt] = __builtin_amdgcn_mfma_f32_16x16x32_bf16(af[mt], bf[nt], acc[4 + mt][nt], 0, 0, 0);
    __builtin_amdgcn_s_setprio(0);

    // boundary: tile j+1 resident; counted waits, wave-uniform, never 0 mid-loop
    if (j < QKV_NT - 1) {
      if (j + 3 < QKV_NT) {
        if (wave < 4) VMW(8); else if (wave < 6) VMW(6); else VMW(4);
      } else if (j + 2 < QKV_NT) {
        if (wave < 4) VMW(4); else if (wave < 6) VMW(3); else VMW(2);
      } else {
        VMW(0);
      }
      __builtin_amdgcn_s_barrier();
    }
  }
#undef STAGE

  // epilogue: per-fragment split at col 1536
#pragma unroll
  for (int nt = 0; nt < 3; nt++) {
    const int fragc = (int)colbase + wn + nt * 16;   // lane-invariant, 16-aligned
    const int col = fragc + l15;
    const float bv = bias[col];
    if (fragc >= 1536) {
      const long bb = rowbase >> 10;
      const int dloc = col - 1536;
      u16* op = vT + (bb * 12 + (dloc >> 6)) * 65536L + (long)(dloc & 63) * 1024;
      const int t0 = (int)(rowbase & 1023) + wm;
#pragma unroll
      for (int mt = 0; mt < 8; mt++) {
        short4v pv;
#pragma unroll
        for (int r = 0; r < 4; r++) pv[r] = (short)f2b(acc[mt][nt][r] + bv);
        *(short4v*)(op + t0 + mt * 16 + q * 4) = pv;
      }
    } else {
#pragma unroll
      for (int mt = 0; mt < 8; mt++)
#pragma unroll
        for (int r = 0; r < 4; r++) {
          const long row = rowbase + wm + mt * 16 + q * 4 + r;
          qkOut[row * 1536 + col] = f2b(acc[mt][nt][r] + bv);
        }
    }
  }
}

// ---------------------------------------------------------------------------
// R14 proj GEMM: out[8192][768] = yatt * wTp^T + b_proj (fp32 out).
// Same pipeline as the 45.5us qkv: tile 256x96, BK=32, 4 slots (88 KiB),
// 768 thr = 12 waves as 4M x 3N (acc[4][2] = 32 regs), grid 32x8 = 256
// blocks = 1/CU, distance-3 prefetch, counted wave-uniform vmcnt, one
// barrier/tile, setprio, same 0-conflict swizzle. Replaces the legacy
// 2-slot gemm_bt_bias (never profiled; estimated 30-45us at ~220-450 TF).
// Per-slot issues: waves 0-3: 3 (A0,A1,B0), waves 4-5: 2 (A0,B0),
// waves 6-11: 1 (A0). Steady wait leaves 2 newest tiles in flight.
// ---------------------------------------------------------------------------
__global__ __launch_bounds__(768, 3) void gemm_proj_96(
    const u16* __restrict__ A, const u16* __restrict__ Bt,
    const float* __restrict__ bias, float* __restrict__ C)
{
  __shared__ __align__(16) u16 sA[4][256 * 32];   // 64 KiB
  __shared__ __align__(16) u16 sB[4][96 * 32];    // 24 KiB

  const int bid = blockIdx.x;
  const int wg = (bid & 7) * 32 + (bid >> 3);
  const int bx = wg & 7;        // col tile 0..7 (96 cols each)
  const int by = wg >> 3;       // row tile 0..31 (256 rows each)

  const int tid = threadIdx.x;
  const int lane = tid & 63;
  const int l15 = lane & 15, q = lane >> 4;
  const int wave = tid >> 6;          // 0..11
  const int wm = (wave / 3) * 64;     // 4 M-groups (4 m-frags each)
  const int wn = (wave % 3) * 32;     // 3 N-groups (2 n-frags each)
  const long rowbase = (long)by * 256;
  const long colbase = (long)bx * 96;
  const int xq = ((q ^ ((l15 >> 1) & 3)) << 3);   // swizzled k-octet (u16)

  // staging chunks (16B): A 1024 chunks, B 384 chunks
  const int cA0 = tid, cA1 = 768 + tid;
  const int cB0 = (tid < 384) ? tid : (tid - 384);   // clamp unused in-range
  const u16* pa0 = A + (rowbase + (cA0 >> 2)) * 768 + ((((cA0 & 3) ^ ((cA0 >> 3) & 3))) << 3);
  const u16* pa1 = A + (rowbase + (cA1 >> 2)) * 768 + ((((cA1 & 3) ^ ((cA1 >> 3) & 3))) << 3);
  const u16* pb0 = Bt + (colbase + (cB0 >> 2)) * 768 + ((((cB0 & 3) ^ ((cB0 >> 3) & 3))) << 3);
  const bool hasA1 = (tid < 256);   // waves 0-3
  const bool hasB0 = (tid < 384);   // waves 0-5

#define PSTAGE(t, s) do { \
    const long k0_ = (long)(t) * 32; \
    gld_lds16(pa0 + k0_, &sA[s][cA0 * 8]); \
    if (hasA1) gld_lds16(pa1 + k0_, &sA[s][cA1 * 8]); \
    if (hasB0) gld_lds16(pb0 + k0_, &sB[s][cB0 * 8]); } while (0)

  floatx4 acc[4][2];
#pragma unroll
  for (int i = 0; i < 4; i++)
#pragma unroll
    for (int n = 0; n < 2; n++) acc[i][n] = (floatx4){0.f, 0.f, 0.f, 0.f};

  PSTAGE(0, 0); PSTAGE(1, 1); PSTAGE(2, 2);
  if (wave < 4) VMW(6); else if (wave < 6) VMW(4); else VMW(2);
  __builtin_amdgcn_s_barrier();

#pragma unroll 4
  for (int j = 0; j < QKV_NT; ++j) {
    const int slot = j & 3;
    const u16* ap = sA[slot];
    const u16* bp = sB[slot];

    short8 bf[2], af[4];
#pragma unroll
    for (int nt = 0; nt < 2; nt++)
      bf[nt] = *(const short8*)(bp + (wn + nt * 16 + l15) * 32 + xq);
#pragma unroll
    for (int mt = 0; mt < 4; mt++)
      af[mt] = *(const short8*)(ap + (wm + mt * 16 + l15) * 32 + xq);
    if (j + 3 < QKV_NT) PSTAGE(j + 3, (j + 3) & 3);
    __builtin_amdgcn_s_setprio(1);
#pragma unroll
    for (int mt = 0; mt < 4; mt++)
#pragma unroll
      for (int nt = 0; nt < 2; nt++)
        acc[mt][nt] = __builtin_amdgcn_mfma_f32_16x16x32_bf16(af[mt], bf[nt], acc[mt][nt], 0, 0, 0);
    __builtin_amdgcn_s_setprio(0);

    if (j < QKV_NT - 1) {
      if (j + 3 < QKV_NT) {
        if (wave < 4) VMW(6); else if (wave < 6) VMW(4); else VMW(2);
      } else if (j + 2 < QKV_NT) {
        if (wave < 4) VMW(3); else if (wave < 6) VMW(2); else VMW(1);
      } else {
        VMW(0);
      }
      __builtin_amdgcn_s_barrier();
    }
  }
#undef PSTAGE

  // epilogue: fp32 out + bias
#pragma unroll
  for (int nt = 0; nt < 2; nt++) {
    const int col = (int)colbase + wn + nt * 16 + l15;
    const float bv = bias[col];
#pragma unroll
    for (int mt = 0; mt < 4; mt++)
#pragma unroll
      for (int r = 0; r < 4; r++) {
        const long row = rowbase + wm + mt * 16 + q * 4 + r;
        C[row * 768 + col] = acc[mt][nt][r] + bv;
      }
  }
}
#undef VMW

// ---------------------------------------------------------------------------
// Flash attention, causal — R10 64-row version VERBATIM (best measured combo;
// the 128-row rewrite was ~6us slower: R10 non-qkv 137.3 vs R11 143.3).
// One block = (b*12+h, q-tile of 64 rows), 256 thr. sV double-buffered.
// ---------------------------------------------------------------------------
__global__ __launch_bounds__(256) void attn_fwd(
    const u16* __restrict__ qk, const u16* __restrict__ vT, u16* __restrict__ y)
{
  const int bh = blockIdx.x;        // b*12 + h
  const int qt = 15 - blockIdx.y;   // reversed: long blocks dispatch first
  const int b = bh / 12, h = bh % 12;
  const long rowOff = (long)b * 1024;
  const int qb = qt * 64;

  __shared__ __align__(16) u16 sK[64 * 72];
  __shared__ __align__(16) u16 sV[2][64 * 72];  // V^T [d][key], double-buffered
  __shared__ __align__(16) u16 sP[64 * 72];     // P [qrow][key]

  const int tid = threadIdx.x;
  const int lane = tid & 63, wave = tid >> 6;
  const int l15 = lane & 15, q = lane >> 4;
  const int qrow_g = qb + wave * 16 + l15;    // this lane's softmax row

  short8 qf[2];
  {
    const u16* qp = qk + (long)(rowOff + qrow_g) * 1536 + h * 64 + q * 8;
    short8 a0 = *(const short8*)(qp);
    short8 a1 = *(const short8*)(qp + 32);
#pragma unroll
    for (int i = 0; i < 8; i++) {
      a0[i] = (short)f2b(b2f((u16)a0[i]) * 0.125f);
      a1[i] = (short)f2b(b2f((u16)a1[i]) * 0.125f);
    }
    qf[0] = a0; qf[1] = a1;
  }

  float m_i = -1e30f, l_i = 0.f;
  floatx4 o[4];
#pragma unroll
  for (int nt = 0; nt < 4; nt++) o[nt] = (floatx4){0.f, 0.f, 0.f, 0.f};

  for (int j = 0; j <= qt; j++) {
    const int jb = j * 64;
    u16* sVc = sV[j & 1];
#pragma unroll
    for (int rep = 0; rep < 2; rep++) {
      int idx = tid + rep * 256;
      int r = idx >> 3, ch = (idx & 7) * 8;
      *(short8*)(sK + r * 72 + ch) =
          *(const short8*)(qk + (long)(rowOff + jb + r) * 1536 + 768 + h * 64 + ch);
      *(short8*)(sVc + r * 72 + ch) =
          *(const short8*)(vT + (long)bh * 65536 + (long)r * 1024 + jb + ch);
    }
    __syncthreads();

    floatx4 sf[4];
#pragma unroll
    for (int mt = 0; mt < 4; mt++) sf[mt] = (floatx4){0.f, 0.f, 0.f, 0.f};
#pragma unroll
    for (int kk = 0; kk < 2; kk++) {
#pragma unroll
      for (int mt = 0; mt < 4; mt++) {
        short8 kf = *(const short8*)(sK + (mt * 16 + l15) * 72 + kk * 32 + q * 8);
        sf[mt] = __builtin_amdgcn_mfma_f32_16x16x32_bf16(kf, qf[kk], sf[mt], 0, 0, 0);
      }
    }

    float mx = m_i;
#pragma unroll
    for (int mt = 0; mt < 4; mt++)
#pragma unroll
      for (int r = 0; r < 4; r++) {
        int key_g = jb + mt * 16 + q * 4 + r;
        float v = sf[mt][r];
        if (key_g > qrow_g) v = -1e30f;
        sf[mt][r] = v;
        mx = fmaxf(mx, v);
      }
    mx = fmaxf(mx, __shfl_xor(mx, 16));
    mx = fmaxf(mx, __shfl_xor(mx, 32));
    float al = __expf(m_i - mx);
    m_i = mx;
    float rsum = 0.f;
#pragma unroll
    for (int mt = 0; mt < 4; mt++) {
      short4v pv;
#pragma unroll
      for (int r = 0; r < 4; r++) {
        float p = __expf(sf[mt][r] - mx);
        rsum += p;
        pv[r] = (short)f2b(p);
      }
      *(short4v*)(sP + (wave * 16 + l15) * 72 + mt * 16 + q * 4) = pv;
    }
    rsum += __shfl_xor(rsum, 16);
    rsum += __shfl_xor(rsum, 32);
    l_i = l_i * al + rsum;
    __syncthreads();   // sP (+ this iter's sV) visible before PV

    float al_r[4];
#pragma unroll
    for (int r = 0; r < 4; r++) al_r[r] = __shfl(al, q * 4 + r);
#pragma unroll
    for (int nt = 0; nt < 4; nt++)
#pragma unroll
      for (int r = 0; r < 4; r++) o[nt][r] *= al_r[r];
#pragma unroll
    for (int kk = 0; kk < 2; kk++) {
      short8 pf = *(const short8*)(sP + (wave * 16 + l15) * 72 + kk * 32 + q * 8);
#pragma unroll
      for (int nt = 0; nt < 4; nt++) {
        short8 vf = *(const short8*)(sVc + (nt * 16 + l15) * 72 + kk * 32 + q * 8);
        o[nt] = __builtin_amdgcn_mfma_f32_16x16x32_bf16(pf, vf, o[nt], 0, 0, 0);
      }
    }
  }

  float linv = 1.f / l_i;
  float li_r[4];
#pragma unroll
  for (int r = 0; r < 4; r++) li_r[r] = __shfl(linv, q * 4 + r);
#pragma unroll
  for (int nt = 0; nt < 4; nt++)
#pragma unroll
    for (int r = 0; r < 4; r++) {
      int row = qb + wave * 16 + q * 4 + r;
      int col = h * 64 + nt * 16 + l15;
      y[(rowOff + row) * 768 + col] = f2b(o[nt][r] * li_r[r]);
    }
}

// ---------------------------------------------------------------------------
extern "C" void kernel_launch(void* const* d_in, const int* in_sizes, int n_in,
                              void* d_out, int out_size, void* d_ws, size_t ws_size,
                              hipStream_t stream) {
  const float* x      = (const float*)d_in[0];  // [8192][768] fp32
  const float* w_attn = (const float*)d_in[1];  // [768][2304] fp32
  const float* b_attn = (const float*)d_in[2];  // [2304] fp32
  const float* w_proj = (const float*)d_in[3];  // [768][768] fp32
  const float* b_proj = (const float*)d_in[4];  // [768] fp32
  float* out = (float*)d_out;                   // [8192][768] fp32

  char* ws = (char*)d_ws;
  u16* xb   = (u16*)ws; ws += (size_t)8192 * 768 * 2;     // 12.6 MB
  u16* wTa  = (u16*)ws; ws += (size_t)2304 * 768 * 2;     //  3.5 MB
  u16* wTp  = (u16*)ws; ws += (size_t)768 * 768 * 2;      //  1.2 MB
  u16* qk   = (u16*)ws; ws += (size_t)8192 * 1536 * 2;    // 25.2 MB (Q|K)
  u16* vT   = (u16*)ws; ws += (size_t)96 * 64 * 1024 * 2; // 12.6 MB (V^T)
  u16* yatt = (u16*)ws; ws += (size_t)8192 * 768 * 2;     // 12.6 MB

  // fused prep: x->bf16 + both weight transposes
  prep<<<dim3(6720), 256, 0, stream>>>(x, xb, w_attn, wTa, w_proj, wTp);

  // qkv GEMM: R11 verbatim (45.5 us measured)
  gemm_qkv_288<<<dim3(256), 768, 0, stream>>>(xb, wTa, b_attn, qk, vT);

  // flash attention: R10 64-row verbatim
  attn_fwd<<<dim3(96, 16), 256, 0, stream>>>(qk, vT, yatt);

  // proj GEMM: 256x96 tiles, grid 256 = 1/CU, qkv-class pipeline
  gemm_proj_96<<<dim3(256), 768, 0, stream>>>(yatt, wTp, b_proj, out);
}

// Round 8
// 178.661 us; speedup vs baseline: 1.3013x; 1.0598x over previous
//
#include <hip/hip_runtime.h>
#include <hip/hip_bf16.h>
#include <stdint.h>

typedef unsigned short u16;
typedef short short8 __attribute__((ext_vector_type(8)));
typedef short short4v __attribute__((ext_vector_type(4)));
typedef float floatx4 __attribute__((ext_vector_type(4)));

__device__ __forceinline__ float b2f(u16 v) {
  union { unsigned int u; float f; } c; c.u = ((unsigned int)v) << 16; return c.f;
}
__device__ __forceinline__ u16 f2b(float f) {
  union { float f; unsigned int u; } c; c.f = f;
  unsigned int u = c.u;
  return (u16)((u + 0x7fffu + ((u >> 16) & 1u)) >> 16);  // RNE
}
// packed f32x2 -> bf16x2 (RNE), single HW instr (no builtin on gfx950)
__device__ __forceinline__ unsigned int cvtpk_bf16(float lo, float hi) {
  unsigned int r;
  asm("v_cvt_pk_bf16_f32 %0, %1, %2" : "=v"(r) : "v"(lo), "v"(hi));
  return r;
}

// async global->LDS, 16B per lane. LDS dest must be wave-uniform base + lane*16.
__device__ __forceinline__ void gld_lds16(const u16* g, u16* l) {
  __builtin_amdgcn_global_load_lds(
      (const __attribute__((address_space(1))) unsigned int*)g,
      (__attribute__((address_space(3))) unsigned int*)l,
      16, 0, 0);
}

// ---------------------------------------------------------------------------
// Fused prep: x fp32->bf16 (blocks 0..6143), w_attn T (6144..6575),
// w_proj T (6576..6719). Transposes also convert fp32->bf16.
// ---------------------------------------------------------------------------
__device__ __forceinline__ void tile_transpose_f2b(
    const float* __restrict__ in, u16* __restrict__ out,
    int inRS, int outRS, int rb, int cb, int tid)
{
  __shared__ __align__(16) u16 t[64][72];
  const int r = tid >> 2, sg = tid & 3;
  const float* ip = in + (long)(rb + r) * inRS + cb + sg * 16;
#pragma unroll
  for (int i = 0; i < 16; i += 4) {
    float4 f = *(const float4*)(ip + i);
    t[r][sg * 16 + i]     = f2b(f.x);
    t[r][sg * 16 + i + 1] = f2b(f.y);
    t[r][sg * 16 + i + 2] = f2b(f.z);
    t[r][sg * 16 + i + 3] = f2b(f.w);
  }
  __syncthreads();
  short8 v0, v1;
#pragma unroll
  for (int i = 0; i < 8; i++) v0[i] = (short)t[sg * 16 + i][r];
#pragma unroll
  for (int i = 0; i < 8; i++) v1[i] = (short)t[sg * 16 + 8 + i][r];
  *(short8*)(out + (long)(cb + r) * outRS + rb + sg * 16)     = v0;
  *(short8*)(out + (long)(cb + r) * outRS + rb + sg * 16 + 8) = v1;
}

__global__ __launch_bounds__(256) void prep(
    const float* __restrict__ x, u16* __restrict__ xb,
    const float* __restrict__ w_attn, u16* __restrict__ wTa,
    const float* __restrict__ w_proj, u16* __restrict__ wTp)
{
  const int bid = blockIdx.x, tid = threadIdx.x;
  if (bid < 6144) {
    int i = (bid * 256 + tid) * 4;
    float4 f = *(const float4*)(x + i);
    short4v v;
    v[0] = (short)f2b(f.x); v[1] = (short)f2b(f.y);
    v[2] = (short)f2b(f.z); v[3] = (short)f2b(f.w);
    *(short4v*)(xb + i) = v;
  } else if (bid < 6576) {
    int t = bid - 6144;                 // 36 x 12 tiles of w_attn [768][2304]
    tile_transpose_f2b(w_attn, wTa, 2304, 768, (t / 36) * 64, (t % 36) * 64, tid);
  } else {
    int t = bid - 6576;                 // 12 x 12 tiles of w_proj [768][768]
    tile_transpose_f2b(w_proj, wTp, 768, 768, (t / 12) * 64, (t % 12) * 64, tid);
  }
}

// ---------------------------------------------------------------------------
// qkv GEMM — R11 version VERBATIM (measured 45.5 us).
// ---------------------------------------------------------------------------
#define QKV_K 768
#define QKV_NT 24   // 768/32
#define VMW(n) asm volatile("s_waitcnt vmcnt(" #n ")" ::: "memory")

__global__ __launch_bounds__(768, 3) void gemm_qkv_288(
    const u16* __restrict__ A, const u16* __restrict__ Bt,
    const float* __restrict__ bias, u16* __restrict__ qkOut, u16* __restrict__ vT)
{
  __shared__ __align__(16) u16 sA[4][256 * 32];   // 64 KiB
  __shared__ __align__(16) u16 sB[4][288 * 32];   // 72 KiB

  const int bid = blockIdx.x;
  const int wg = (bid & 7) * 32 + (bid >> 3);
  const int bx = wg & 7;        // col tile 0..7 (288 cols each)
  const int by = wg >> 3;       // row tile 0..31 (256 rows each)

  const int tid = threadIdx.x;
  const int lane = tid & 63;
  const int l15 = lane & 15, q = lane >> 4;
  const int wave = tid >> 6;          // 0..11
  const int wm = (wave / 6) * 128;    // 2 M-groups
  const int wn = (wave % 6) * 48;     // 6 N-groups (3 frags each)
  const long rowbase = (long)by * 256;
  const long colbase = (long)bx * 288;
  const int xq = ((q ^ ((l15 >> 1) & 3)) << 3);   // swizzled k-octet (u16)

  const int cA0 = tid, cA1 = 768 + tid;   // A: 1024 chunks (waves 0-3 take 2nd)
  const int cB0 = tid, cB1 = 768 + tid;   // B: 1152 chunks (waves 0-5 take 2nd)
  const u16* pa0 = A + (rowbase + (cA0 >> 2)) * QKV_K + ((((cA0 & 3) ^ ((cA0 >> 3) & 3))) << 3);
  const u16* pa1 = A + (rowbase + (cA1 >> 2)) * QKV_K + ((((cA1 & 3) ^ ((cA1 >> 3) & 3))) << 3);
  const u16* pb0 = Bt + (colbase + (cB0 >> 2)) * QKV_K + ((((cB0 & 3) ^ ((cB0 >> 3) & 3))) << 3);
  const u16* pb1 = Bt + (colbase + (cB1 >> 2)) * QKV_K + ((((cB1 & 3) ^ ((cB1 >> 3) & 3))) << 3);
  const bool hasA1 = (tid < 256);   // wave-uniform (waves 0-3)
  const bool hasB1 = (tid < 384);   // wave-uniform (waves 0-5)

#define STAGE(t, s) do { \
    const long k0_ = (long)(t) * 32; \
    gld_lds16(pa0 + k0_, &sA[s][cA0 * 8]); \
    if (hasA1) gld_lds16(pa1 + k0_, &sA[s][cA1 * 8]); \
    gld_lds16(pb0 + k0_, &sB[s][cB0 * 8]); \
    if (hasB1) gld_lds16(pb1 + k0_, &sB[s][cB1 * 8]); } while (0)

  floatx4 acc[8][3];
#pragma unroll
  for (int i = 0; i < 8; i++)
#pragma unroll
    for (int n = 0; n < 3; n++) acc[i][n] = (floatx4){0.f, 0.f, 0.f, 0.f};

  STAGE(0, 0); STAGE(1, 1); STAGE(2, 2);
  if (wave < 4) VMW(8); else if (wave < 6) VMW(6); else VMW(4);
  __builtin_amdgcn_s_barrier();   // all waves' tile-0 resident

#pragma unroll 4
  for (int j = 0; j < QKV_NT; ++j) {
    const int slot = j & 3;
    const u16* ap = sA[slot];
    const u16* bp = sB[slot];

    // phase A: 7 ds_reads, stage tile j+3, 12 MFMA
    short8 bf[3];
#pragma unroll
    for (int nt = 0; nt < 3; nt++)
      bf[nt] = *(const short8*)(bp + (wn + nt * 16 + l15) * 32 + xq);
    short8 af[4];
#pragma unroll
    for (int mt = 0; mt < 4; mt++)
      af[mt] = *(const short8*)(ap + (wm + mt * 16 + l15) * 32 + xq);
    if (j + 3 < QKV_NT) STAGE(j + 3, (j + 3) & 3);
    __builtin_amdgcn_s_setprio(1);
#pragma unroll
    for (int mt = 0; mt < 4; mt++)
#pragma unroll
      for (int nt = 0; nt < 3; nt++)
        acc[mt][nt] = __builtin_amdgcn_mfma_f32_16x16x32_bf16(af[mt], bf[nt], acc[mt][nt], 0, 0, 0);
    __builtin_amdgcn_s_setprio(0);

    // phase B: 4 ds_reads, 12 MFMA
#pragma unroll
    for (int mt = 0; mt < 4; mt++)
      af[mt] = *(const short8*)(ap + (wm + 64 + mt * 16 + l15) * 32 + xq);
    __builtin_amdgcn_s_setprio(1);
#pragma unroll
    for (int mt = 0; mt < 4; mt++)
#pragma unroll
      for (int nt = 0; nt < 3; nt++)
        acc[4 + mt][nt] = __builtin_amdgcn_mfma_f32_16x16x32_bf16(af[mt], bf[nt], acc[4 + mt][nt], 0, 0, 0);
    __builtin_amdgcn_s_setprio(0);

    // boundary: tile j+1 resident; counted waits, wave-uniform, never 0 mid-loop
    if (j < QKV_NT - 1) {
      if (j + 3 < QKV_NT) {
        if (wave < 4) VMW(8); else if (wave < 6) VMW(6); else VMW(4);
      } else if (j + 2 < QKV_NT) {
        if (wave < 4) VMW(4); else if (wave < 6) VMW(3); else VMW(2);
      } else {
        VMW(0);
      }
      __builtin_amdgcn_s_barrier();
    }
  }
#undef STAGE

  // epilogue: per-fragment split at col 1536
#pragma unroll
  for (int nt = 0; nt < 3; nt++) {
    const int fragc = (int)colbase + wn + nt * 16;   // lane-invariant, 16-aligned
    const int col = fragc + l15;
    const float bv = bias[col];
    if (fragc >= 1536) {
      const long bb = rowbase >> 10;
      const int dloc = col - 1536;
      u16* op = vT + (bb * 12 + (dloc >> 6)) * 65536L + (long)(dloc & 63) * 1024;
      const int t0 = (int)(rowbase & 1023) + wm;
#pragma unroll
      for (int mt = 0; mt < 8; mt++) {
        short4v pv;
#pragma unroll
        for (int r = 0; r < 4; r++) pv[r] = (short)f2b(acc[mt][nt][r] + bv);
        *(short4v*)(op + t0 + mt * 16 + q * 4) = pv;
      }
    } else {
#pragma unroll
      for (int mt = 0; mt < 8; mt++)
#pragma unroll
        for (int r = 0; r < 4; r++) {
          const long row = rowbase + wm + mt * 16 + q * 4 + r;
          qkOut[row * 1536 + col] = f2b(acc[mt][nt][r] + bv);
        }
    }
  }
}

// ---------------------------------------------------------------------------
// proj GEMM — R14 version VERBATIM (not in top-5 => fast enough for now).
// ---------------------------------------------------------------------------
__global__ __launch_bounds__(768, 3) void gemm_proj_96(
    const u16* __restrict__ A, const u16* __restrict__ Bt,
    const float* __restrict__ bias, float* __restrict__ C)
{
  __shared__ __align__(16) u16 sA[4][256 * 32];   // 64 KiB
  __shared__ __align__(16) u16 sB[4][96 * 32];    // 24 KiB

  const int bid = blockIdx.x;
  const int wg = (bid & 7) * 32 + (bid >> 3);
  const int bx = wg & 7;        // col tile 0..7 (96 cols each)
  const int by = wg >> 3;       // row tile 0..31 (256 rows each)

  const int tid = threadIdx.x;
  const int lane = tid & 63;
  const int l15 = lane & 15, q = lane >> 4;
  const int wave = tid >> 6;          // 0..11
  const int wm = (wave / 3) * 64;     // 4 M-groups (4 m-frags each)
  const int wn = (wave % 3) * 32;     // 3 N-groups (2 n-frags each)
  const long rowbase = (long)by * 256;
  const long colbase = (long)bx * 96;
  const int xq = ((q ^ ((l15 >> 1) & 3)) << 3);   // swizzled k-octet (u16)

  const int cA0 = tid, cA1 = 768 + tid;
  const int cB0 = (tid < 384) ? tid : (tid - 384);   // clamp unused in-range
  const u16* pa0 = A + (rowbase + (cA0 >> 2)) * 768 + ((((cA0 & 3) ^ ((cA0 >> 3) & 3))) << 3);
  const u16* pa1 = A + (rowbase + (cA1 >> 2)) * 768 + ((((cA1 & 3) ^ ((cA1 >> 3) & 3))) << 3);
  const u16* pb0 = Bt + (colbase + (cB0 >> 2)) * 768 + ((((cB0 & 3) ^ ((cB0 >> 3) & 3))) << 3);
  const bool hasA1 = (tid < 256);   // waves 0-3
  const bool hasB0 = (tid < 384);   // waves 0-5

#define PSTAGE(t, s) do { \
    const long k0_ = (long)(t) * 32; \
    gld_lds16(pa0 + k0_, &sA[s][cA0 * 8]); \
    if (hasA1) gld_lds16(pa1 + k0_, &sA[s][cA1 * 8]); \
    if (hasB0) gld_lds16(pb0 + k0_, &sB[s][cB0 * 8]); } while (0)

  floatx4 acc[4][2];
#pragma unroll
  for (int i = 0; i < 4; i++)
#pragma unroll
    for (int n = 0; n < 2; n++) acc[i][n] = (floatx4){0.f, 0.f, 0.f, 0.f};

  PSTAGE(0, 0); PSTAGE(1, 1); PSTAGE(2, 2);
  if (wave < 4) VMW(6); else if (wave < 6) VMW(4); else VMW(2);
  __builtin_amdgcn_s_barrier();

#pragma unroll 4
  for (int j = 0; j < QKV_NT; ++j) {
    const int slot = j & 3;
    const u16* ap = sA[slot];
    const u16* bp = sB[slot];

    short8 bf[2], af[4];
#pragma unroll
    for (int nt = 0; nt < 2; nt++)
      bf[nt] = *(const short8*)(bp + (wn + nt * 16 + l15) * 32 + xq);
#pragma unroll
    for (int mt = 0; mt < 4; mt++)
      af[mt] = *(const short8*)(ap + (wm + mt * 16 + l15) * 32 + xq);
    if (j + 3 < QKV_NT) PSTAGE(j + 3, (j + 3) & 3);
    __builtin_amdgcn_s_setprio(1);
#pragma unroll
    for (int mt = 0; mt < 4; mt++)
#pragma unroll
      for (int nt = 0; nt < 2; nt++)
        acc[mt][nt] = __builtin_amdgcn_mfma_f32_16x16x32_bf16(af[mt], bf[nt], acc[mt][nt], 0, 0, 0);
    __builtin_amdgcn_s_setprio(0);

    if (j < QKV_NT - 1) {
      if (j + 3 < QKV_NT) {
        if (wave < 4) VMW(6); else if (wave < 6) VMW(4); else VMW(2);
      } else if (j + 2 < QKV_NT) {
        if (wave < 4) VMW(3); else if (wave < 6) VMW(2); else VMW(1);
      } else {
        VMW(0);
      }
      __builtin_amdgcn_s_barrier();
    }
  }
#undef PSTAGE

#pragma unroll
  for (int nt = 0; nt < 2; nt++) {
    const int col = (int)colbase + wn + nt * 16 + l15;
    const float bv = bias[col];
#pragma unroll
    for (int mt = 0; mt < 4; mt++)
#pragma unroll
      for (int r = 0; r < 4; r++) {
        const long row = rowbase + wm + mt * 16 + q * 4 + r;
        C[row * 768 + col] = acc[mt][nt][r] + bv;
      }
  }
}
#undef VMW

// ---------------------------------------------------------------------------
// R15 flash attention: R10 64-row structure, VALU-slimmed softmax.
//   - exp2 domain: qf prescaled by 0.125*log2(e); p = exp2(s-m) via native
//     v_exp_f32 (removes the hidden mul in every __expf).
//   - v_cvt_pk_bf16_f32 for the P->bf16 store (16 manual RNE f2b ~64 VALU ->
//     8 instrs; same RNE rounding, bit-identical).
//   - defer-max (T13, THR=8 in log2 domain): when __all(tile_max <= m+8),
//     keep m, skip o-rescale (16 mul + 4 bpermute) and the al exp.
//     P bounded by 2^8=256 -- fine in bf16/f32 accumulation.
// ---------------------------------------------------------------------------
__global__ __launch_bounds__(256) void attn_fwd(
    const u16* __restrict__ qk, const u16* __restrict__ vT, u16* __restrict__ y)
{
  const int bh = blockIdx.x;        // b*12 + h
  const int qt = 15 - blockIdx.y;   // reversed: long blocks dispatch first
  const int b = bh / 12, h = bh % 12;
  const long rowOff = (long)b * 1024;
  const int qb = qt * 64;

  __shared__ __align__(16) u16 sK[64 * 72];
  __shared__ __align__(16) u16 sV[2][64 * 72];  // V^T [d][key], double-buffered
  __shared__ __align__(16) u16 sP[64 * 72];     // P [qrow][key]

  const int tid = threadIdx.x;
  const int lane = tid & 63, wave = tid >> 6;
  const int l15 = lane & 15, q = lane >> 4;
  const int qrow_g = qb + wave * 16 + l15;    // this lane's softmax row

  // Q fragments, pre-scaled by (1/8)*log2(e) => scores land in log2 domain
  short8 qf[2];
  {
    const float qs = 0.125f * 1.44269504f;
    const u16* qp = qk + (long)(rowOff + qrow_g) * 1536 + h * 64 + q * 8;
    short8 a0 = *(const short8*)(qp);
    short8 a1 = *(const short8*)(qp + 32);
#pragma unroll
    for (int i = 0; i < 8; i++) {
      a0[i] = (short)f2b(b2f((u16)a0[i]) * qs);
      a1[i] = (short)f2b(b2f((u16)a1[i]) * qs);
    }
    qf[0] = a0; qf[1] = a1;
  }

  float m_i = -1e30f, l_i = 0.f;
  floatx4 o[4];
#pragma unroll
  for (int nt = 0; nt < 4; nt++) o[nt] = (floatx4){0.f, 0.f, 0.f, 0.f};

  for (int j = 0; j <= qt; j++) {
    const int jb = j * 64;
    u16* sVc = sV[j & 1];
#pragma unroll
    for (int rep = 0; rep < 2; rep++) {
      int idx = tid + rep * 256;
      int r = idx >> 3, ch = (idx & 7) * 8;
      *(short8*)(sK + r * 72 + ch) =
          *(const short8*)(qk + (long)(rowOff + jb + r) * 1536 + 768 + h * 64 + ch);
      *(short8*)(sVc + r * 72 + ch) =
          *(const short8*)(vT + (long)bh * 65536 + (long)r * 1024 + jb + ch);
    }
    __syncthreads();

    floatx4 sf[4];
#pragma unroll
    for (int mt = 0; mt < 4; mt++) sf[mt] = (floatx4){0.f, 0.f, 0.f, 0.f};
#pragma unroll
    for (int kk = 0; kk < 2; kk++) {
#pragma unroll
      for (int mt = 0; mt < 4; mt++) {
        short8 kf = *(const short8*)(sK + (mt * 16 + l15) * 72 + kk * 32 + q * 8);
        sf[mt] = __builtin_amdgcn_mfma_f32_16x16x32_bf16(kf, qf[kk], sf[mt], 0, 0, 0);
      }
    }

    // causal mask + tile max (log2 domain)
    float tmx = -1e30f;
#pragma unroll
    for (int mt = 0; mt < 4; mt++)
#pragma unroll
      for (int r = 0; r < 4; r++) {
        int key_g = jb + mt * 16 + q * 4 + r;
        float v = sf[mt][r];
        if (key_g > qrow_g) v = -1e30f;
        sf[mt][r] = v;
        tmx = fmaxf(tmx, v);
      }
    tmx = fmaxf(tmx, __shfl_xor(tmx, 16));
    tmx = fmaxf(tmx, __shfl_xor(tmx, 32));

    // defer-max: skip rescale when all rows' growth <= 8 (P bounded by 256)
    const bool defer = __all(tmx <= m_i + 8.0f);
    float al = 1.0f;
    float mx = m_i;
    if (!defer) {
      mx = fmaxf(m_i, tmx);
      al = __builtin_amdgcn_exp2f(m_i - mx);
      m_i = mx;
    }

    float rsum = 0.f;
#pragma unroll
    for (int mt = 0; mt < 4; mt++) {
      float p0 = __builtin_amdgcn_exp2f(sf[mt][0] - mx);
      float p1 = __builtin_amdgcn_exp2f(sf[mt][1] - mx);
      float p2 = __builtin_amdgcn_exp2f(sf[mt][2] - mx);
      float p3 = __builtin_amdgcn_exp2f(sf[mt][3] - mx);
      rsum += (p0 + p1) + (p2 + p3);
      unsigned int w0 = cvtpk_bf16(p0, p1);
      unsigned int w1 = cvtpk_bf16(p2, p3);
      uint2 pw; pw.x = w0; pw.y = w1;
      *(uint2*)(sP + (wave * 16 + l15) * 72 + mt * 16 + q * 4) = pw;
    }
    rsum += __shfl_xor(rsum, 16);
    rsum += __shfl_xor(rsum, 32);
    l_i = l_i * al + rsum;
    __syncthreads();   // sP (+ this iter's sV) visible before PV

    if (!defer) {
      float al_r[4];
#pragma unroll
      for (int r = 0; r < 4; r++) al_r[r] = __shfl(al, q * 4 + r);
#pragma unroll
      for (int nt = 0; nt < 4; nt++)
#pragma unroll
        for (int r = 0; r < 4; r++) o[nt][r] *= al_r[r];
    }
#pragma unroll
    for (int kk = 0; kk < 2; kk++) {
      short8 pf = *(const short8*)(sP + (wave * 16 + l15) * 72 + kk * 32 + q * 8);
#pragma unroll
      for (int nt = 0; nt < 4; nt++) {
        short8 vf = *(const short8*)(sVc + (nt * 16 + l15) * 72 + kk * 32 + q * 8);
        o[nt] = __builtin_amdgcn_mfma_f32_16x16x32_bf16(pf, vf, o[nt], 0, 0, 0);
      }
    }
  }

  float linv = 1.f / l_i;
  float li_r[4];
#pragma unroll
  for (int r = 0; r < 4; r++) li_r[r] = __shfl(linv, q * 4 + r);
#pragma unroll
  for (int nt = 0; nt < 4; nt++)
#pragma unroll
    for (int r = 0; r < 4; r++) {
      int row = qb + wave * 16 + q * 4 + r;
      int col = h * 64 + nt * 16 + l15;
      y[(rowOff + row) * 768 + col] = f2b(o[nt][r] * li_r[r]);
    }
}

// ---------------------------------------------------------------------------
extern "C" void kernel_launch(void* const* d_in, const int* in_sizes, int n_in,
                              void* d_out, int out_size, void* d_ws, size_t ws_size,
                              hipStream_t stream) {
  const float* x      = (const float*)d_in[0];  // [8192][768] fp32
  const float* w_attn = (const float*)d_in[1];  // [768][2304] fp32
  const float* b_attn = (const float*)d_in[2];  // [2304] fp32
  const float* w_proj = (const float*)d_in[3];  // [768][768] fp32
  const float* b_proj = (const float*)d_in[4];  // [768] fp32
  float* out = (float*)d_out;                   // [8192][768] fp32

  char* ws = (char*)d_ws;
  u16* xb   = (u16*)ws; ws += (size_t)8192 * 768 * 2;     // 12.6 MB
  u16* wTa  = (u16*)ws; ws += (size_t)2304 * 768 * 2;     //  3.5 MB
  u16* wTp  = (u16*)ws; ws += (size_t)768 * 768 * 2;      //  1.2 MB
  u16* qk   = (u16*)ws; ws += (size_t)8192 * 1536 * 2;    // 25.2 MB (Q|K)
  u16* vT   = (u16*)ws; ws += (size_t)96 * 64 * 1024 * 2; // 12.6 MB (V^T)
  u16* yatt = (u16*)ws; ws += (size_t)8192 * 768 * 2;     // 12.6 MB

  // fused prep: x->bf16 + both weight transposes
  prep<<<dim3(6720), 256, 0, stream>>>(x, xb, w_attn, wTa, w_proj, wTp);

  // qkv GEMM: R11 verbatim (45.5 us measured)
  gemm_qkv_288<<<dim3(256), 768, 0, stream>>>(xb, wTa, b_attn, qk, vT);

  // flash attention: 64-row tiles, VALU-slimmed softmax (exp2 + cvt_pk + defer-max)
  attn_fwd<<<dim3(96, 16), 256, 0, stream>>>(qk, vT, yatt);

  // proj GEMM: 256x96 tiles, grid 256 = 1/CU, qkv-class pipeline
  gemm_proj_96<<<dim3(256), 768, 0, stream>>>(yatt, wTp, b_proj, out);
}